// Round 1
// baseline (120.446 us; speedup 1.0000x reference)
//
#include <hip/hip_runtime.h>
#include <hip/hip_bf16.h>

// Problem constants (from reference setup_inputs): B=16, D=256, T_enC=512, T_deC=2048
#define NB 16
#define ND 256
#define NK 512    // T_enc (contraction dim)
#define NT 2048   // T_dec (output cols)

// Tile config: BM=128, BN=128, BK=32, 256 threads (4 waves, 2x2 wave grid,
// each wave computes 64x64 via 4x4 grid of 16x16x32 bf16 MFMAs).
#define BM 128
#define BN 128
#define BK 32
#define RSA 40   // A LDS row stride in bf16 (80B: 16B-aligned for b128, 2-way banks)
#define RSB 36   // B^T LDS row stride in bf16 (72B = 18 dwords: <=2-way banks on b64)

typedef __attribute__((ext_vector_type(8))) short short8;   // 8 bf16 = 4 VGPRs
typedef __attribute__((ext_vector_type(4))) float f32x4;    // MFMA accumulator

union S8U { short8 v; uint2 u[2]; };
union BF2U { __hip_bfloat162 h; unsigned int u; };

__device__ inline unsigned int pack2bf(float a, float b) {
    BF2U c; c.h = __float22bfloat162_rn(make_float2(a, b));
    return c.u;
}

__global__ __launch_bounds__(256, 2)
void bmm_bf16_mfma(const float* __restrict__ x, const float* __restrict__ path,
                   float* __restrict__ out) {
    const int n0 = blockIdx.x * BN;
    const int m0 = blockIdx.y * BM;
    const int b  = blockIdx.z;
    const int t    = threadIdx.x;
    const int lane = t & 63;
    const int wv   = t >> 6;          // wave id 0..3
    const int wr   = (wv >> 1) * 64;  // wave row offset in tile
    const int wc   = (wv & 1) * 64;   // wave col offset in tile
    const int q    = lane >> 4;       // quad 0..3
    const int lm   = lane & 15;

    __shared__ unsigned short As[BM * RSA]; // [m][k], k-contiguous
    __shared__ unsigned short Bs[BN * RSB]; // [n][k] (transposed), k-contiguous

    const float* xg = x    + ((size_t)b * ND + m0) * NK;        // A tile base
    const float* pg = path + (size_t)b * NK * NT + n0;          // B tile base (row k0.., col n0..)

    f32x4 acc[4][4];
#pragma unroll
    for (int i = 0; i < 4; ++i)
#pragma unroll
        for (int j = 0; j < 4; ++j)
            acc[i][j] = (f32x4){0.f, 0.f, 0.f, 0.f};

    for (int k0 = 0; k0 < NK; k0 += BK) {
        // ---- Stage A: 128x32 fp32 -> bf16 LDS. float4 loads, b64 LDS writes.
#pragma unroll
        for (int i = 0; i < 4; ++i) {
            int f   = t + i * 256;       // 0..1023 float4s
            int row = f >> 3;            // 8 float4 per 32-wide row
            int c4  = f & 7;
            float4 v = *reinterpret_cast<const float4*>(xg + (size_t)row * NK + k0 + c4 * 4);
            uint2 p;
            p.x = pack2bf(v.x, v.y);
            p.y = pack2bf(v.z, v.w);
            *reinterpret_cast<uint2*>(&As[row * RSA + c4 * 4]) = p;
        }
        // ---- Stage B (transposed): lane-stride-1 scalar loads so lane owns one n;
        // pack 4 k-values -> one b64 write into Bs[n][k]. Conflict-free (<=2-way).
#pragma unroll
        for (int i = 0; i < 4; ++i) {
            int p   = wv * 4 + i;        // 0..15
            int kr4 = p >> 1;            // 0..7 : group of 4 k-rows
            int ng  = p & 1;             // 0..1 : n half
            int n   = ng * 64 + lane;
            const float* src = pg + (size_t)(k0 + kr4 * 4) * NT + n;
            float f0 = src[0 * NT];
            float f1 = src[1 * NT];
            float f2 = src[2 * NT];
            float f3 = src[3 * NT];
            uint2 pk;
            pk.x = pack2bf(f0, f1);
            pk.y = pack2bf(f2, f3);
            *reinterpret_cast<uint2*>(&Bs[n * RSB + kr4 * 4]) = pk;
        }
        __syncthreads();

        // ---- Fragments + MFMA
        short8 af[4];
        short8 bfr[4];
#pragma unroll
        for (int mt = 0; mt < 4; ++mt) {
            int row = wr + mt * 16 + lm;
            af[mt] = *reinterpret_cast<const short8*>(&As[row * RSA + q * 8]); // 16B aligned
        }
#pragma unroll
        for (int nt = 0; nt < 4; ++nt) {
            int n = wc + nt * 16 + lm;
            S8U s;
            s.u[0] = *reinterpret_cast<const uint2*>(&Bs[n * RSB + q * 8]);
            s.u[1] = *reinterpret_cast<const uint2*>(&Bs[n * RSB + q * 8 + 4]);
            bfr[nt] = s.v;
        }
#pragma unroll
        for (int mt = 0; mt < 4; ++mt)
#pragma unroll
            for (int nt = 0; nt < 4; ++nt)
                acc[mt][nt] = __builtin_amdgcn_mfma_f32_16x16x32_bf16(
                    af[mt], bfr[nt], acc[mt][nt], 0, 0, 0);

        __syncthreads();
    }

    // ---- Epilogue: C/D layout col=lane&15, row=(lane>>4)*4+reg  [m89-verified]
    float* og = out + ((size_t)b * ND + m0 + wr) * NT + n0 + wc;
#pragma unroll
    for (int mt = 0; mt < 4; ++mt) {
#pragma unroll
        for (int r = 0; r < 4; ++r) {
            int row = mt * 16 + q * 4 + r;
#pragma unroll
            for (int nt = 0; nt < 4; ++nt) {
                int col = nt * 16 + lm;
                og[(size_t)row * NT + col] = acc[mt][nt][r];
            }
        }
    }
}

extern "C" void kernel_launch(void* const* d_in, const int* in_sizes, int n_in,
                              void* d_out, int out_size, void* d_ws, size_t ws_size,
                              hipStream_t stream) {
    const float* x    = (const float*)d_in[0];   // [16, 256, 512]
    const float* path = (const float*)d_in[1];   // [16, 512, 2048]
    float* out        = (float*)d_out;           // [16, 256, 2048]
    dim3 grid(NT / BN, ND / BM, NB);             // (16, 2, 16) = 512 blocks
    dim3 block(256);
    bmm_bf16_mfma<<<grid, block, 0, stream>>>(x, path, out);
}